// Round 2
// baseline (1473.176 us; speedup 1.0000x reference)
//
#include <hip/hip_runtime.h>

// ---------------------------------------------------------------------------
// Swin-style transformer block, MI355X (gfx950).
// Chunked pipeline (rows chunked by M_C divisible by 128 and 9):
//   cvt weights->bf16 | per chunk: LN1 | QKV GEMM | 9x9 window attention |
//   proj GEMM+res | LN2 | FC1 GEMM+GELU | FC2 GEMM+res | dwconv9
// GEMMs: bf16 MFMA 16x16x32, 128x128 tile, BK=64, 4 waves, global_load_lds.
// Workspace need = 6.3MB + M_C*10240 bytes; M_C chosen to fit ws_size.
// ---------------------------------------------------------------------------

typedef short short8 __attribute__((ext_vector_type(8)));
typedef unsigned short ushort8 __attribute__((ext_vector_type(8)));
typedef float floatx4 __attribute__((ext_vector_type(4)));

static constexpr int R_TOT = 73728;  // 8192 windows * 9 tokens

__device__ __forceinline__ unsigned short f2bf(float f) {
  union { float f; unsigned int u; } v; v.f = f;
  unsigned int r = v.u + 0x7FFFu + ((v.u >> 16) & 1u);
  return (unsigned short)(r >> 16);
}
__device__ __forceinline__ float bf2f(unsigned short u) {
  union { unsigned int u; float f; } v; v.u = ((unsigned int)u) << 16;
  return v.f;
}

__device__ __forceinline__ void gload_lds16(const void* g, void* l) {
  __builtin_amdgcn_global_load_lds(
      (const __attribute__((address_space(1))) unsigned int*)g,
      (__attribute__((address_space(3))) unsigned int*)l, 16, 0, 0);
}

// --------------------------- weight f32 -> bf16 ----------------------------
__global__ __launch_bounds__(256)
void cvt4(const float* __restrict__ in, unsigned short* __restrict__ out) {
  int i = (blockIdx.x * 256 + threadIdx.x) * 4;
  floatx4 v = *(const floatx4*)(in + i);
  union { unsigned short s[4]; unsigned long long u; } pk;
  pk.s[0] = f2bf(v[0]); pk.s[1] = f2bf(v[1]); pk.s[2] = f2bf(v[2]); pk.s[3] = f2bf(v[3]);
  *(unsigned long long*)(out + i) = pk.u;
}

// ------------------------------- LayerNorm ---------------------------------
__global__ __launch_bounds__(256)
void ln_bf16(const float* __restrict__ in, const float* __restrict__ g,
             const float* __restrict__ b, unsigned short* __restrict__ out) {
  const int lane = threadIdx.x & 63;
  const int wid = threadIdx.x >> 6;
  const size_t row = (size_t)blockIdx.x * 4 + wid;
  const float* p = in + row * 512 + lane * 8;
  floatx4 v0 = *(const floatx4*)p;
  floatx4 v1 = *(const floatx4*)(p + 4);
  float s = v0[0] + v0[1] + v0[2] + v0[3] + v1[0] + v1[1] + v1[2] + v1[3];
  float ss = v0[0]*v0[0] + v0[1]*v0[1] + v0[2]*v0[2] + v0[3]*v0[3]
           + v1[0]*v1[0] + v1[1]*v1[1] + v1[2]*v1[2] + v1[3]*v1[3];
  #pragma unroll
  for (int m = 1; m < 64; m <<= 1) { s += __shfl_xor(s, m); ss += __shfl_xor(ss, m); }
  float mu = s * (1.f / 512.f);
  float var = ss * (1.f / 512.f) - mu * mu;
  float rs = rsqrtf(var + 1e-5f);
  const float* gp = g + lane * 8;
  const float* bp = b + lane * 8;
  floatx4 g0 = *(const floatx4*)gp, g1 = *(const floatx4*)(gp + 4);
  floatx4 b0 = *(const floatx4*)bp, b1 = *(const floatx4*)(bp + 4);
  ushort8 o;
  o[0] = f2bf((v0[0] - mu) * rs * g0[0] + b0[0]);
  o[1] = f2bf((v0[1] - mu) * rs * g0[1] + b0[1]);
  o[2] = f2bf((v0[2] - mu) * rs * g0[2] + b0[2]);
  o[3] = f2bf((v0[3] - mu) * rs * g0[3] + b0[3]);
  o[4] = f2bf((v1[0] - mu) * rs * g1[0] + b1[0]);
  o[5] = f2bf((v1[1] - mu) * rs * g1[1] + b1[1]);
  o[6] = f2bf((v1[2] - mu) * rs * g1[2] + b1[2]);
  o[7] = f2bf((v1[3] - mu) * rs * g1[3] + b1[3]);
  *(ushort8*)(out + row * 512 + lane * 8) = o;
}

// ------------------------------ GEMM (A @ W^T) -----------------------------
template <int EPI>
__global__ __launch_bounds__(256)
void gemm_bt(const unsigned short* __restrict__ A,
             const unsigned short* __restrict__ W,
             const float* __restrict__ bias,
             const float* __restrict__ resid,
             unsigned short* __restrict__ outb,
             float* __restrict__ outf,
             int K, int Nn) {
  __shared__ unsigned short As[128 * 64];
  __shared__ unsigned short Bs[128 * 64];

  const int t = threadIdx.x;
  const int lane = t & 63;
  const int wid = t >> 6;
  const int wr = wid >> 1;
  const int wc = wid & 1;

  const size_t rowB = (size_t)blockIdx.y * 128;
  const size_t colB = (size_t)blockIdx.x * 128;

  floatx4 acc[4][4];
  #pragma unroll
  for (int m = 0; m < 4; ++m)
    #pragma unroll
    for (int n = 0; n < 4; ++n)
      acc[m][n] = (floatx4){0.f, 0.f, 0.f, 0.f};

  const int ar = t >> 3;
  const int ac = (t & 7) * 8;
  const unsigned short* Abase = A + (rowB + ar) * (size_t)K + ac;
  const unsigned short* Wbase = W + (colB + ar) * (size_t)K + ac;
  const size_t K32 = (size_t)K * 32;

  const int la = lane & 15;
  const int lk = (lane >> 4) * 8;

  for (int ks = 0; ks < K; ks += 64) {
    #pragma unroll
    for (int c = 0; c < 4; ++c) {
      gload_lds16(Abase + ks + c * K32, &As[c * 2048 + t * 8]);
      gload_lds16(Wbase + ks + c * K32, &Bs[c * 2048 + t * 8]);
    }
    __syncthreads();
    #pragma unroll
    for (int kk = 0; kk < 2; ++kk) {
      short8 aF[4], bF[4];
      #pragma unroll
      for (int m = 0; m < 4; ++m)
        aF[m] = *(const short8*)&As[(wr * 64 + m * 16 + la) * 64 + kk * 32 + lk];
      #pragma unroll
      for (int n = 0; n < 4; ++n)
        bF[n] = *(const short8*)&Bs[(wc * 64 + n * 16 + la) * 64 + kk * 32 + lk];
      #pragma unroll
      for (int m = 0; m < 4; ++m)
        #pragma unroll
        for (int n = 0; n < 4; ++n)
          acc[m][n] = __builtin_amdgcn_mfma_f32_16x16x32_bf16(aF[m], bF[n], acc[m][n], 0, 0, 0);
    }
    __syncthreads();
  }

  const int r0 = (int)rowB + wr * 64;
  const int c0 = (int)colB + wc * 64;
  #pragma unroll
  for (int m = 0; m < 4; ++m) {
    #pragma unroll
    for (int n = 0; n < 4; ++n) {
      #pragma unroll
      for (int j = 0; j < 4; ++j) {
        int r = r0 + m * 16 + (lane >> 4) * 4 + j;
        int c = c0 + n * 16 + la;
        float v = acc[m][n][j] + bias[c];
        if (EPI == 1) v = 0.5f * v * (1.0f + erff(v * 0.70710678118654752f));
        if (EPI == 2) {
          v += resid[(size_t)r * Nn + c];
          outf[(size_t)r * Nn + c] = v;
        } else {
          outb[(size_t)r * Nn + c] = f2bf(v);
        }
      }
    }
  }
}

// -------------------------- window attention (9x9) -------------------------
__global__ __launch_bounds__(256)
void attn9(const unsigned short* __restrict__ qkv,
           const float* __restrict__ bias_table,
           unsigned short* __restrict__ out) {
  __shared__ float qL[4][9][64];
  __shared__ float kL[4][9][64];
  __shared__ float vL[4][9][64];
  __shared__ float sL[4][9][10];

  const int lane = threadIdx.x & 63;
  const int wid = threadIdx.x >> 6;
  const int bh = blockIdx.x * 4 + wid;
  const int b = bh >> 3;
  const int h = bh & 7;

  const size_t base = (size_t)b * 9 * 1536 + h * 64 + lane;
  #pragma unroll
  for (int i = 0; i < 9; ++i) {
    qL[wid][i][lane] = bf2f(qkv[base + i * 1536]) * 0.125f;
    kL[wid][i][lane] = bf2f(qkv[base + i * 1536 + 512]);
    vL[wid][i][lane] = bf2f(qkv[base + i * 1536 + 1024]);
  }
  __syncthreads();

  #pragma unroll
  for (int p = 0; p < 2; ++p) {
    int pair = lane + p * 64;
    if (pair < 81) {
      int i = pair / 9, j = pair % 9;
      const floatx4* qi = (const floatx4*)qL[wid][i];
      const floatx4* kj = (const floatx4*)kL[wid][j];
      float dot = 0.f;
      #pragma unroll
      for (int d = 0; d < 16; ++d) {
        floatx4 a = qi[d], c = kj[d];
        dot += a[0]*c[0] + a[1]*c[1] + a[2]*c[2] + a[3]*c[3];
      }
      int dy = i / 3 - j / 3 + 2;
      int dx = i % 3 - j % 3 + 2;
      dot += bias_table[(dy * 5 + dx) * 8 + h];
      sL[wid][i][j] = dot;
    }
  }
  __syncthreads();

  if (lane < 9) {
    float m = -1e30f;
    #pragma unroll
    for (int j = 0; j < 9; ++j) m = fmaxf(m, sL[wid][lane][j]);
    float e[9], sum = 0.f;
    #pragma unroll
    for (int j = 0; j < 9; ++j) { e[j] = __expf(sL[wid][lane][j] - m); sum += e[j]; }
    float inv = 1.f / sum;
    #pragma unroll
    for (int j = 0; j < 9; ++j) sL[wid][lane][j] = e[j] * inv;
  }
  __syncthreads();

  const size_t obase = (size_t)b * 9 * 512 + h * 64 + lane;
  #pragma unroll
  for (int i = 0; i < 9; ++i) {
    float a = 0.f;
    #pragma unroll
    for (int j = 0; j < 9; ++j) a += sL[wid][i][j] * vL[wid][j][lane];
    out[obase + i * 512] = f2bf(a);
  }
}

// -------------------- depthwise 3x3 merge conv (9 -> 1) --------------------
__global__ __launch_bounds__(256)
void dwconv9(const float* __restrict__ x2, const float* __restrict__ wc,
             const float* __restrict__ bc, float* __restrict__ out) {
  int idx = blockIdx.x * 256 + threadIdx.x;  // local: b*512 + c
  int c = idx & 511;
  int b = idx >> 9;
  const float* xp = x2 + (size_t)b * 9 * 512 + c;
  float acc = bc[c];
  #pragma unroll
  for (int t = 0; t < 9; ++t) acc += xp[t * 512] * wc[c * 9 + t];
  out[idx] = acc;
}

// ---------------------------------------------------------------------------
extern "C" void kernel_launch(void* const* d_in, const int* in_sizes, int n_in,
                              void* d_out, int out_size, void* d_ws, size_t ws_size,
                              hipStream_t stream) {
  const float* x      = (const float*)d_in[0];
  const float* gamma1 = (const float*)d_in[1];
  const float* beta1  = (const float*)d_in[2];
  const float* w_qkv  = (const float*)d_in[3];
  const float* b_qkv  = (const float*)d_in[4];
  const float* bias_t = (const float*)d_in[5];
  const float* w_proj = (const float*)d_in[6];
  const float* b_proj = (const float*)d_in[7];
  const float* gamma2 = (const float*)d_in[8];
  const float* beta2  = (const float*)d_in[9];
  const float* w_fc1  = (const float*)d_in[10];
  const float* b_fc1  = (const float*)d_in[11];
  const float* w_fc2  = (const float*)d_in[12];
  const float* b_fc2  = (const float*)d_in[13];
  const float* w_conv = (const float*)d_in[14];
  const float* b_conv = (const float*)d_in[15];
  float* out = (float*)d_out;

  // ---- adaptive chunking: need = 6.29MB + M_C*10240 bytes ----
  static const int cand[6] = {73728, 36864, 18432, 9216, 4608, 2304};
  int M_C = 2304;
  for (int i = 0; i < 6; ++i) {
    size_t need = 6291456ull + (size_t)cand[i] * 10240ull;
    if (need <= ws_size) { M_C = cand[i]; break; }
  }
  const int nChunks = R_TOT / M_C;
  const int winC = M_C / 9;

  char* ws = (char*)d_ws;
  unsigned short* wqkvb  = (unsigned short*)(ws);
  unsigned short* wprojb = (unsigned short*)(ws + 1572864);
  unsigned short* wfc1b  = (unsigned short*)(ws + 2097152);
  unsigned short* wfc2b  = (unsigned short*)(ws + 4194304);
  char* base = ws + 6291456;
  const size_t szHB  = (size_t)M_C * 1024;   // M_C*512 bf16
  const size_t szQKV = (size_t)M_C * 3072;   // M_C*1536 bf16
  const size_t szX1  = (size_t)M_C * 2048;   // M_C*512 f32
  unsigned short* hb   = (unsigned short*)base;                 // also aob
  unsigned short* aob  = hb;
  unsigned short* qkvb = (unsigned short*)(base + szHB);
  unsigned short* h2b  = qkvb;                                  // reuse
  float* x2            = (float*)(base + szHB + szHB);          // inside qkvb region
  float* x1            = (float*)(base + szHB + szQKV);
  unsigned short* gb   = (unsigned short*)(base + szHB + szQKV + szX1);

  // 1. weights -> bf16 (once)
  cvt4<<<768, 256, 0, stream>>>(w_qkv, wqkvb);
  cvt4<<<256, 256, 0, stream>>>(w_proj, wprojb);
  cvt4<<<1024, 256, 0, stream>>>(w_fc1, wfc1b);
  cvt4<<<1024, 256, 0, stream>>>(w_fc2, wfc2b);

  for (int ch = 0; ch < nChunks; ++ch) {
    const size_t rOff = (size_t)ch * M_C;
    const float* xC = x + rOff * 512;
    float* outC = out + (size_t)ch * winC * 512;
    const int mt = M_C / 128;

    ln_bf16<<<M_C / 4, 256, 0, stream>>>(xC, gamma1, beta1, hb);
    gemm_bt<0><<<dim3(12, mt), 256, 0, stream>>>(hb, wqkvb, b_qkv, nullptr, qkvb, nullptr, 512, 1536);
    attn9<<<winC * 2, 256, 0, stream>>>(qkvb, bias_t, aob);
    gemm_bt<2><<<dim3(4, mt), 256, 0, stream>>>(aob, wprojb, b_proj, xC, nullptr, x1, 512, 512);
    ln_bf16<<<M_C / 4, 256, 0, stream>>>(x1, gamma2, beta2, h2b);
    gemm_bt<1><<<dim3(16, mt), 256, 0, stream>>>(h2b, wfc1b, b_fc1, nullptr, gb, nullptr, 512, 2048);
    gemm_bt<2><<<dim3(4, mt), 256, 0, stream>>>(gb, wfc2b, b_fc2, x1, nullptr, x2, 2048, 512);
    dwconv9<<<winC * 2, 256, 0, stream>>>(x2, w_conv, b_conv, outC);
  }
}

// Round 3
// 1372.325 us; speedup vs baseline: 1.0735x; 1.0735x over previous
//
#include <hip/hip_runtime.h>

// ---------------------------------------------------------------------------
// Swin-style transformer block, MI355X (gfx950).
// GEMMs: 256x256 tile, BK=64, 8 waves, 8-phase pipelined schedule with
// counted vmcnt (T3+T4), setprio around MFMA (T5), slot-XOR LDS swizzle (T2),
// global_load_lds 16B staging (linear dest + inverse-swizzled source).
// ---------------------------------------------------------------------------

typedef short short8 __attribute__((ext_vector_type(8)));
typedef unsigned short ushort8 __attribute__((ext_vector_type(8)));
typedef float floatx4 __attribute__((ext_vector_type(4)));

static constexpr int R_TOT = 73728;  // 8192 windows * 9 tokens

__device__ __forceinline__ unsigned short f2bf(float f) {
  union { float f; unsigned int u; } v; v.f = f;
  unsigned int r = v.u + 0x7FFFu + ((v.u >> 16) & 1u);
  return (unsigned short)(r >> 16);
}
__device__ __forceinline__ float bf2f(unsigned short u) {
  union { unsigned int u; float f; } v; v.u = ((unsigned int)u) << 16;
  return v.f;
}

__device__ __forceinline__ void gload_lds16(const void* g, void* l) {
  __builtin_amdgcn_global_load_lds(
      (const __attribute__((address_space(1))) unsigned int*)g,
      (__attribute__((address_space(3))) unsigned int*)l, 16, 0, 0);
}

#define FENCE asm volatile("" ::: "memory")
#define BAR do { FENCE; __builtin_amdgcn_s_barrier(); FENCE; } while (0)
#define WAITV0 asm volatile("s_waitcnt vmcnt(0)" ::: "memory")
#define WAITV4 asm volatile("s_waitcnt vmcnt(4)" ::: "memory")
#define WAITV8 asm volatile("s_waitcnt vmcnt(8)" ::: "memory")

// --------------------------- weight f32 -> bf16 ----------------------------
__global__ __launch_bounds__(256)
void cvt4(const float* __restrict__ in, unsigned short* __restrict__ out) {
  int i = (blockIdx.x * 256 + threadIdx.x) * 4;
  floatx4 v = *(const floatx4*)(in + i);
  union { unsigned short s[4]; unsigned long long u; } pk;
  pk.s[0] = f2bf(v[0]); pk.s[1] = f2bf(v[1]); pk.s[2] = f2bf(v[2]); pk.s[3] = f2bf(v[3]);
  *(unsigned long long*)(out + i) = pk.u;
}

// ------------------------------- LayerNorm ---------------------------------
__global__ __launch_bounds__(256)
void ln_bf16(const float* __restrict__ in, const float* __restrict__ g,
             const float* __restrict__ b, unsigned short* __restrict__ out) {
  const int lane = threadIdx.x & 63;
  const int wid = threadIdx.x >> 6;
  const size_t row = (size_t)blockIdx.x * 4 + wid;
  const float* p = in + row * 512 + lane * 8;
  floatx4 v0 = *(const floatx4*)p;
  floatx4 v1 = *(const floatx4*)(p + 4);
  float s = v0[0] + v0[1] + v0[2] + v0[3] + v1[0] + v1[1] + v1[2] + v1[3];
  float ss = v0[0]*v0[0] + v0[1]*v0[1] + v0[2]*v0[2] + v0[3]*v0[3]
           + v1[0]*v1[0] + v1[1]*v1[1] + v1[2]*v1[2] + v1[3]*v1[3];
  #pragma unroll
  for (int m = 1; m < 64; m <<= 1) { s += __shfl_xor(s, m); ss += __shfl_xor(ss, m); }
  float mu = s * (1.f / 512.f);
  float var = ss * (1.f / 512.f) - mu * mu;
  float rs = rsqrtf(var + 1e-5f);
  const float* gp = g + lane * 8;
  const float* bp = b + lane * 8;
  floatx4 g0 = *(const floatx4*)gp, g1 = *(const floatx4*)(gp + 4);
  floatx4 b0 = *(const floatx4*)bp, b1 = *(const floatx4*)(bp + 4);
  ushort8 o;
  o[0] = f2bf((v0[0] - mu) * rs * g0[0] + b0[0]);
  o[1] = f2bf((v0[1] - mu) * rs * g0[1] + b0[1]);
  o[2] = f2bf((v0[2] - mu) * rs * g0[2] + b0[2]);
  o[3] = f2bf((v0[3] - mu) * rs * g0[3] + b0[3]);
  o[4] = f2bf((v1[0] - mu) * rs * g1[0] + b1[0]);
  o[5] = f2bf((v1[1] - mu) * rs * g1[1] + b1[1]);
  o[6] = f2bf((v1[2] - mu) * rs * g1[2] + b1[2]);
  o[7] = f2bf((v1[3] - mu) * rs * g1[3] + b1[3]);
  *(ushort8*)(out + row * 512 + lane * 8) = o;
}

// ------------------- 8-phase 256x256 GEMM (A @ W^T) ------------------------
// A: (M x K) bf16 rm. Wp: (Nn x K) bf16 rm. EPI 0: +bias->bf16.
// EPI 1: +bias,GELU->bf16. EPI 2: +bias+resid(f32)->f32.
// LDS: A arena [d][q(64rows)][wm][8 subtiles x 1024B], B arena
// [d][hb(32cols)][wn][4 subtiles x 1024B]; slot-XOR swizzle within subtile.

#define STAGE_A(d, qq, tk) do { \
  gload_lds16(Ap + (rowB + (qq)*64 + rowU) * (size_t)K + (tk) + kofsU, \
              sm + (d)*32768 + (qq)*16384 + wid*1024); \
  gload_lds16(Ap + (rowB + 128 + (qq)*64 + rowU) * (size_t)K + (tk) + kofsU, \
              sm + (d)*32768 + (qq)*16384 + 8192 + wid*1024); \
} while (0)

#define STAGE_B(d, hb, tk) do { \
  gload_lds16(Wp + (colB + (wid>>2)*64 + (hb)*32 + colU) * (size_t)K + (tk) + kofsU, \
              sm + 65536 + (d)*32768 + (hb)*16384 + wid*1024); \
  gload_lds16(Wp + (colB + (2 + (wid>>2))*64 + (hb)*32 + colU) * (size_t)K + (tk) + kofsU, \
              sm + 65536 + (d)*32768 + (hb)*16384 + 8192 + wid*1024); \
} while (0)

#define LOAD_A(d, qq) do { \
  _Pragma("unroll") \
  for (int fl = 0; fl < 4; ++fl) { \
    aF[fl][0] = *(const short8*)(sm + (d)*32768 + (qq)*16384 + wm*8192 + (fl*2+0)*1024 + laneRD); \
    aF[fl][1] = *(const short8*)(sm + (d)*32768 + (qq)*16384 + wm*8192 + (fl*2+1)*1024 + laneRD); \
  } \
} while (0)

#define LOAD_B(d, hb, BF) do { \
  _Pragma("unroll") \
  for (int nl = 0; nl < 2; ++nl) { \
    BF[nl][0] = *(const short8*)(sm + 65536 + (d)*32768 + (hb)*16384 + wn*4096 + (nl*2+0)*1024 + laneRD); \
    BF[nl][1] = *(const short8*)(sm + 65536 + (d)*32768 + (hb)*16384 + wn*4096 + (nl*2+1)*1024 + laneRD); \
  } \
} while (0)

#define MMQ(qa, hb, BF) do { \
  __builtin_amdgcn_s_setprio(1); \
  _Pragma("unroll") \
  for (int fl = 0; fl < 4; ++fl) \
    _Pragma("unroll") \
    for (int nl = 0; nl < 2; ++nl) { \
      acc[(qa)*4+fl][(hb)*2+nl] = __builtin_amdgcn_mfma_f32_16x16x32_bf16(aF[fl][0], BF[nl][0], acc[(qa)*4+fl][(hb)*2+nl], 0, 0, 0); \
      acc[(qa)*4+fl][(hb)*2+nl] = __builtin_amdgcn_mfma_f32_16x16x32_bf16(aF[fl][1], BF[nl][1], acc[(qa)*4+fl][(hb)*2+nl], 0, 0, 0); \
    } \
  __builtin_amdgcn_s_setprio(0); \
} while (0)

template <int EPI>
__global__ __launch_bounds__(512, 2)
void gemm8p(const unsigned short* __restrict__ Ap,
            const unsigned short* __restrict__ Wp,
            const float* __restrict__ bias,
            const float* __restrict__ resid,
            unsigned short* __restrict__ outb,
            float* __restrict__ outf,
            int K, int Nn, int ntn) {
  __shared__ __align__(16) char sm[131072];

  const int t = threadIdx.x;
  const int l = t & 63;
  const int wid = t >> 6;
  const int wm = wid >> 2;   // 0..1
  const int wn = wid & 3;    // 0..3

  // bijective XCD-aware swizzle
  const int nwg = gridDim.x;
  const int orig = blockIdx.x;
  const int q8 = nwg >> 3, r8 = nwg & 7;
  const int xcd = orig & 7, idx = orig >> 3;
  const int wg = (xcd < r8 ? xcd * (q8 + 1) : r8 * (q8 + 1) + (xcd - r8) * q8) + idx;
  const int tm = wg / ntn, tn = wg % ntn;
  const size_t rowB = (size_t)tm * 256;
  const size_t colB = (size_t)tn * 256;

  // staging lane geometry (linear LDS dest; source pre-swizzled)
  const int rowU = (wid >> 1) * 16 + (l >> 2);            // A: row within 64-row unit
  const int colU = ((wid >> 1) & 1) * 16 + (l >> 2);      // B: col within 32-col unit
  const int kofsU = (wid & 1) * 32 + (((l & 3) ^ ((l >> 4) & 3)) * 8);
  // ds_read lane offset (applies the same slot-XOR)
  const int laneRD = (l & 15) * 64 + (((l >> 4) ^ ((l >> 2) & 3)) * 16);

  floatx4 acc[8][4];
  #pragma unroll
  for (int m = 0; m < 8; ++m)
    #pragma unroll
    for (int n = 0; n < 4; ++n)
      acc[m][n] = (floatx4){0.f, 0.f, 0.f, 0.f};

  short8 aF[4][2], bF0[2][2], bF1[2][2];

  // prologue: stage tiles 0 (dbuf0, k=0) and 1 (dbuf1, k=64)
  STAGE_A(0, 0, 0);  STAGE_A(0, 1, 0);  STAGE_B(0, 0, 0);  STAGE_B(0, 1, 0);
  STAGE_A(1, 0, 64); STAGE_A(1, 1, 64); STAGE_B(1, 0, 64); STAGE_B(1, 1, 64);
  WAITV8; BAR;

  const int NI = K >> 7;
  for (int i = 0; i < NI; ++i) {
    const int tk1 = i * 128 + 64;
    const int tk2 = i * 128 + 128;
    const int tk3 = i * 128 + 192;
    const bool pre = (i > 0);
    const bool nxt = (i < NI - 1);

    // ph1: d0 (qa0, hb0)
    LOAD_A(0, 0); LOAD_B(0, 0, bF0);
    if (pre) STAGE_A(1, 1, tk1);
    BAR; MMQ(0, 0, bF0); BAR;
    // ph2: d0 (qa0, hb1)
    LOAD_B(0, 1, bF1);
    if (pre) STAGE_B(1, 0, tk1);
    BAR; MMQ(0, 1, bF1); BAR;
    // ph3: d0 (qa1, hb1)
    LOAD_A(0, 1);
    if (nxt) STAGE_A(0, 0, tk2);
    BAR; MMQ(1, 1, bF1); BAR;
    // ph4: d0 (qa1, hb0)
    if (nxt) STAGE_B(0, 1, tk2);
    BAR; MMQ(1, 0, bF0);
    if (nxt) { WAITV4; } else { WAITV0; }
    BAR;
    // ph5: d1 (qa0, hb0)
    LOAD_A(1, 0); LOAD_B(1, 0, bF0);
    if (nxt) STAGE_A(0, 1, tk2);
    BAR; MMQ(0, 0, bF0); BAR;
    // ph6: d1 (qa0, hb1)
    LOAD_B(1, 1, bF1);
    if (nxt) STAGE_B(0, 0, tk2);
    BAR; MMQ(0, 1, bF1); BAR;
    // ph7: d1 (qa1, hb1)
    LOAD_A(1, 1);
    if (nxt) STAGE_A(1, 0, tk3);
    BAR; MMQ(1, 1, bF1); BAR;
    // ph8: d1 (qa1, hb0)
    if (nxt) STAGE_B(1, 1, tk3);
    BAR; MMQ(1, 0, bF0);
    if (nxt) { WAITV4; }
    BAR;
  }
  FENCE;

  // epilogue
  #pragma unroll
  for (int mi = 0; mi < 8; ++mi) {
    #pragma unroll
    for (int ni = 0; ni < 4; ++ni) {
      const int rr = (int)rowB + wm * 128 + (mi >> 2) * 64 + (mi & 3) * 16 + (l >> 4) * 4;
      const int cc = (int)colB + wn * 64 + (ni >> 1) * 32 + (ni & 1) * 16 + (l & 15);
      const float bs = bias[cc];
      #pragma unroll
      for (int j = 0; j < 4; ++j) {
        float v = acc[mi][ni][j] + bs;
        if (EPI == 1) v = 0.5f * v * (1.0f + erff(v * 0.70710678118654752f));
        if (EPI == 2) {
          v += resid[(size_t)(rr + j) * Nn + cc];
          outf[(size_t)(rr + j) * Nn + cc] = v;
        } else {
          outb[(size_t)(rr + j) * Nn + cc] = f2bf(v);
        }
      }
    }
  }
}

// -------------------------- window attention (9x9) -------------------------
__global__ __launch_bounds__(256)
void attn9(const unsigned short* __restrict__ qkv,
           const float* __restrict__ bias_table,
           unsigned short* __restrict__ out) {
  __shared__ float qL[4][9][64];
  __shared__ float kL[4][9][64];
  __shared__ float vL[4][9][64];
  __shared__ float sL[4][9][10];

  const int lane = threadIdx.x & 63;
  const int wid = threadIdx.x >> 6;
  const int bh = blockIdx.x * 4 + wid;
  const int b = bh >> 3;
  const int h = bh & 7;

  const size_t base = (size_t)b * 9 * 1536 + h * 64 + lane;
  #pragma unroll
  for (int i = 0; i < 9; ++i) {
    qL[wid][i][lane] = bf2f(qkv[base + i * 1536]) * 0.125f;
    kL[wid][i][lane] = bf2f(qkv[base + i * 1536 + 512]);
    vL[wid][i][lane] = bf2f(qkv[base + i * 1536 + 1024]);
  }
  __syncthreads();

  #pragma unroll
  for (int p = 0; p < 2; ++p) {
    int pair = lane + p * 64;
    if (pair < 81) {
      int i = pair / 9, j = pair % 9;
      const floatx4* qi = (const floatx4*)qL[wid][i];
      const floatx4* kj = (const floatx4*)kL[wid][j];
      float dot = 0.f;
      #pragma unroll
      for (int d = 0; d < 16; ++d) {
        floatx4 a = qi[d], c = kj[d];
        dot += a[0]*c[0] + a[1]*c[1] + a[2]*c[2] + a[3]*c[3];
      }
      int dy = i / 3 - j / 3 + 2;
      int dx = i % 3 - j % 3 + 2;
      dot += bias_table[(dy * 5 + dx) * 8 + h];
      sL[wid][i][j] = dot;
    }
  }
  __syncthreads();

  if (lane < 9) {
    float m = -1e30f;
    #pragma unroll
    for (int j = 0; j < 9; ++j) m = fmaxf(m, sL[wid][lane][j]);
    float e[9], sum = 0.f;
    #pragma unroll
    for (int j = 0; j < 9; ++j) { e[j] = __expf(sL[wid][lane][j] - m); sum += e[j]; }
    float inv = 1.f / sum;
    #pragma unroll
    for (int j = 0; j < 9; ++j) sL[wid][lane][j] = e[j] * inv;
  }
  __syncthreads();

  const size_t obase = (size_t)b * 9 * 512 + h * 64 + lane;
  #pragma unroll
  for (int i = 0; i < 9; ++i) {
    float a = 0.f;
    #pragma unroll
    for (int j = 0; j < 9; ++j) a += sL[wid][i][j] * vL[wid][j][lane];
    out[obase + i * 512] = f2bf(a);
  }
}

// -------------------- depthwise 3x3 merge conv (9 -> 1) --------------------
__global__ __launch_bounds__(256)
void dwconv9(const float* __restrict__ x2, const float* __restrict__ wc,
             const float* __restrict__ bc, float* __restrict__ out) {
  int idx = blockIdx.x * 256 + threadIdx.x;  // local: b*512 + c
  int c = idx & 511;
  int b = idx >> 9;
  const float* xp = x2 + (size_t)b * 9 * 512 + c;
  float acc = bc[c];
  #pragma unroll
  for (int t = 0; t < 9; ++t) acc += xp[t * 512] * wc[c * 9 + t];
  out[idx] = acc;
}

// ---------------------------------------------------------------------------
extern "C" void kernel_launch(void* const* d_in, const int* in_sizes, int n_in,
                              void* d_out, int out_size, void* d_ws, size_t ws_size,
                              hipStream_t stream) {
  const float* x      = (const float*)d_in[0];
  const float* gamma1 = (const float*)d_in[1];
  const float* beta1  = (const float*)d_in[2];
  const float* w_qkv  = (const float*)d_in[3];
  const float* b_qkv  = (const float*)d_in[4];
  const float* bias_t = (const float*)d_in[5];
  const float* w_proj = (const float*)d_in[6];
  const float* b_proj = (const float*)d_in[7];
  const float* gamma2 = (const float*)d_in[8];
  const float* beta2  = (const float*)d_in[9];
  const float* w_fc1  = (const float*)d_in[10];
  const float* b_fc1  = (const float*)d_in[11];
  const float* w_fc2  = (const float*)d_in[12];
  const float* b_fc2  = (const float*)d_in[13];
  const float* w_conv = (const float*)d_in[14];
  const float* b_conv = (const float*)d_in[15];
  float* out = (float*)d_out;

  // ---- adaptive chunking: need = 6.29MB + M_C*10240 bytes ----
  static const int cand[6] = {73728, 36864, 18432, 9216, 4608, 2304};
  int M_C = 2304;
  for (int i = 0; i < 6; ++i) {
    size_t need = 6291456ull + (size_t)cand[i] * 10240ull;
    if (need <= ws_size) { M_C = cand[i]; break; }
  }
  const int nChunks = R_TOT / M_C;
  const int winC = M_C / 9;

  char* ws = (char*)d_ws;
  unsigned short* wqkvb  = (unsigned short*)(ws);
  unsigned short* wprojb = (unsigned short*)(ws + 1572864);
  unsigned short* wfc1b  = (unsigned short*)(ws + 2097152);
  unsigned short* wfc2b  = (unsigned short*)(ws + 4194304);
  char* base = ws + 6291456;
  const size_t szHB  = (size_t)M_C * 1024;   // M_C*512 bf16
  const size_t szQKV = (size_t)M_C * 3072;   // M_C*1536 bf16
  const size_t szX1  = (size_t)M_C * 2048;   // M_C*512 f32
  unsigned short* hb   = (unsigned short*)base;                 // also aob
  unsigned short* aob  = hb;
  unsigned short* qkvb = (unsigned short*)(base + szHB);
  unsigned short* h2b  = qkvb;                                  // reuse
  float* x2            = (float*)(base + szHB + szHB);          // inside qkvb region
  float* x1            = (float*)(base + szHB + szQKV);
  unsigned short* gb   = (unsigned short*)(base + szHB + szQKV + szX1);

  // 1. weights -> bf16 (once)
  cvt4<<<768, 256, 0, stream>>>(w_qkv, wqkvb);
  cvt4<<<256, 256, 0, stream>>>(w_proj, wprojb);
  cvt4<<<1024, 256, 0, stream>>>(w_fc1, wfc1b);
  cvt4<<<1024, 256, 0, stream>>>(w_fc2, wfc2b);

  const int mt256 = M_C / 256;
  for (int ch = 0; ch < nChunks; ++ch) {
    const size_t rOff = (size_t)ch * M_C;
    const float* xC = x + rOff * 512;
    float* outC = out + (size_t)ch * winC * 512;

    ln_bf16<<<M_C / 4, 256, 0, stream>>>(xC, gamma1, beta1, hb);
    gemm8p<0><<<dim3(mt256 * 6), 512, 0, stream>>>(hb, wqkvb, b_qkv, nullptr, qkvb, nullptr, 512, 1536, 6);
    attn9<<<winC * 2, 256, 0, stream>>>(qkvb, bias_t, aob);
    gemm8p<2><<<dim3(mt256 * 2), 512, 0, stream>>>(aob, wprojb, b_proj, xC, nullptr, x1, 512, 512, 2);
    ln_bf16<<<M_C / 4, 256, 0, stream>>>(x1, gamma2, beta2, h2b);
    gemm8p<1><<<dim3(mt256 * 8), 512, 0, stream>>>(h2b, wfc1b, b_fc1, nullptr, gb, nullptr, 512, 2048, 8);
    gemm8p<2><<<dim3(mt256 * 2), 512, 0, stream>>>(gb, wfc2b, b_fc2, x1, nullptr, x2, 2048, 512, 2);
    dwconv9<<<winC * 2, 256, 0, stream>>>(x2, w_conv, b_conv, outC);
  }
}

// Round 4
// 1371.806 us; speedup vs baseline: 1.0739x; 1.0004x over previous
//
#include <hip/hip_runtime.h>

// ---------------------------------------------------------------------------
// Swin-style transformer block, MI355X (gfx950).
// GEMMs: 256x256 tile, BK=64, 8 waves, 8-phase schedule, counted vmcnt,
// setprio, granule-XOR LDS swizzle (involution: store (row, kg^(row&7)),
// read (row, kg_wanted^(row&7)) -> conflict-free column reads, exact k-map).
// ---------------------------------------------------------------------------

typedef short short8 __attribute__((ext_vector_type(8)));
typedef unsigned short ushort8 __attribute__((ext_vector_type(8)));
typedef float floatx4 __attribute__((ext_vector_type(4)));

static constexpr int R_TOT = 73728;  // 8192 windows * 9 tokens

__device__ __forceinline__ unsigned short f2bf(float f) {
  union { float f; unsigned int u; } v; v.f = f;
  unsigned int r = v.u + 0x7FFFu + ((v.u >> 16) & 1u);
  return (unsigned short)(r >> 16);
}
__device__ __forceinline__ float bf2f(unsigned short u) {
  union { unsigned int u; float f; } v; v.u = ((unsigned int)u) << 16;
  return v.f;
}

__device__ __forceinline__ void gload_lds16(const void* g, void* l) {
  __builtin_amdgcn_global_load_lds(
      (const __attribute__((address_space(1))) unsigned int*)g,
      (__attribute__((address_space(3))) unsigned int*)l, 16, 0, 0);
}

#define FENCE asm volatile("" ::: "memory")
#define BAR do { FENCE; __builtin_amdgcn_s_barrier(); FENCE; } while (0)
#define WAITV0 asm volatile("s_waitcnt vmcnt(0)" ::: "memory")
#define WAITV4 asm volatile("s_waitcnt vmcnt(4)" ::: "memory")
#define WAITV8 asm volatile("s_waitcnt vmcnt(8)" ::: "memory")

// --------------------------- weight f32 -> bf16 ----------------------------
__global__ __launch_bounds__(256)
void cvt4(const float* __restrict__ in, unsigned short* __restrict__ out) {
  int i = (blockIdx.x * 256 + threadIdx.x) * 4;
  floatx4 v = *(const floatx4*)(in + i);
  union { unsigned short s[4]; unsigned long long u; } pk;
  pk.s[0] = f2bf(v[0]); pk.s[1] = f2bf(v[1]); pk.s[2] = f2bf(v[2]); pk.s[3] = f2bf(v[3]);
  *(unsigned long long*)(out + i) = pk.u;
}

// ------------------------------- LayerNorm ---------------------------------
__global__ __launch_bounds__(256)
void ln_bf16(const float* __restrict__ in, const float* __restrict__ g,
             const float* __restrict__ b, unsigned short* __restrict__ out) {
  const int lane = threadIdx.x & 63;
  const int wid = threadIdx.x >> 6;
  const size_t row = (size_t)blockIdx.x * 4 + wid;
  const float* p = in + row * 512 + lane * 8;
  floatx4 v0 = *(const floatx4*)p;
  floatx4 v1 = *(const floatx4*)(p + 4);
  float s = v0[0] + v0[1] + v0[2] + v0[3] + v1[0] + v1[1] + v1[2] + v1[3];
  float ss = v0[0]*v0[0] + v0[1]*v0[1] + v0[2]*v0[2] + v0[3]*v0[3]
           + v1[0]*v1[0] + v1[1]*v1[1] + v1[2]*v1[2] + v1[3]*v1[3];
  #pragma unroll
  for (int m = 1; m < 64; m <<= 1) { s += __shfl_xor(s, m); ss += __shfl_xor(ss, m); }
  float mu = s * (1.f / 512.f);
  float var = ss * (1.f / 512.f) - mu * mu;
  float rs = rsqrtf(var + 1e-5f);
  const float* gp = g + lane * 8;
  const float* bp = b + lane * 8;
  floatx4 g0 = *(const floatx4*)gp, g1 = *(const floatx4*)(gp + 4);
  floatx4 b0 = *(const floatx4*)bp, b1 = *(const floatx4*)(bp + 4);
  ushort8 o;
  o[0] = f2bf((v0[0] - mu) * rs * g0[0] + b0[0]);
  o[1] = f2bf((v0[1] - mu) * rs * g0[1] + b0[1]);
  o[2] = f2bf((v0[2] - mu) * rs * g0[2] + b0[2]);
  o[3] = f2bf((v0[3] - mu) * rs * g0[3] + b0[3]);
  o[4] = f2bf((v1[0] - mu) * rs * g1[0] + b1[0]);
  o[5] = f2bf((v1[1] - mu) * rs * g1[1] + b1[1]);
  o[6] = f2bf((v1[2] - mu) * rs * g1[2] + b1[2]);
  o[7] = f2bf((v1[3] - mu) * rs * g1[3] + b1[3]);
  *(ushort8*)(out + row * 512 + lane * 8) = o;
}

// ------------------- 8-phase 256x256 GEMM (A @ W^T) ------------------------
// LDS per dbuf d: A units u=0..3 (64 rows x 64 k, 8KB) at d*65536+u*8192;
// B units at +32768. Swizzle: LDS (row, kg) holds global (row, kg^(row&7)).

#define STAGE_AU(d, u, tk) \
  gload_lds16(Ap + (rowB + (u)*64 + srow) * (size_t)K + (tk) + skofs, \
              sm + (d)*65536 + (u)*8192 + wid*1024)
#define STAGE_BU(d, u, tk) \
  gload_lds16(Wp + (colB + (u)*64 + srow) * (size_t)K + (tk) + skofs, \
              sm + (d)*65536 + 32768 + (u)*8192 + wid*1024)

#define LOAD_A(d, mh) do { \
  _Pragma("unroll") \
  for (int fl = 0; fl < 4; ++fl) { \
    aF[fl][0] = *(const short8*)(sm + (d)*65536 + (wm*2+(mh))*8192 + fl*2048 + aoff0); \
    aF[fl][1] = *(const short8*)(sm + (d)*65536 + (wm*2+(mh))*8192 + fl*2048 + aoff1); \
  } \
} while (0)

#define LOAD_B(d, nh, BF) do { \
  _Pragma("unroll") \
  for (int nl = 0; nl < 2; ++nl) { \
    BF[nl][0] = *(const short8*)(sm + (d)*65536 + 32768 + wn*8192 + ((nh)*2+nl)*2048 + aoff0); \
    BF[nl][1] = *(const short8*)(sm + (d)*65536 + 32768 + wn*8192 + ((nh)*2+nl)*2048 + aoff1); \
  } \
} while (0)

#define MMQ(mh, nh, BF) do { \
  __builtin_amdgcn_s_setprio(1); \
  _Pragma("unroll") \
  for (int fl = 0; fl < 4; ++fl) \
    _Pragma("unroll") \
    for (int nl = 0; nl < 2; ++nl) { \
      acc[(mh)*4+fl][(nh)*2+nl] = __builtin_amdgcn_mfma_f32_16x16x32_bf16(aF[fl][0], BF[nl][0], acc[(mh)*4+fl][(nh)*2+nl], 0, 0, 0); \
      acc[(mh)*4+fl][(nh)*2+nl] = __builtin_amdgcn_mfma_f32_16x16x32_bf16(aF[fl][1], BF[nl][1], acc[(mh)*4+fl][(nh)*2+nl], 0, 0, 0); \
    } \
  __builtin_amdgcn_s_setprio(0); \
} while (0)

template <int EPI>
__global__ __launch_bounds__(512, 2)
void gemm8p(const unsigned short* __restrict__ Ap,
            const unsigned short* __restrict__ Wp,
            const float* __restrict__ bias,
            const float* __restrict__ resid,
            unsigned short* __restrict__ outb,
            float* __restrict__ outf,
            int K, int Nn, int ntn) {
  __shared__ __align__(16) char sm[131072];

  const int t = threadIdx.x;
  const int l = t & 63;
  const int wid = t >> 6;
  const int wm = wid >> 2;   // 0..1 (128-row half)
  const int wn = wid & 3;    // 0..3 (64-col unit)

  // bijective XCD-aware swizzle (m204)
  const int nwg = gridDim.x;
  const int orig = blockIdx.x;
  const int q8 = nwg >> 3, r8 = nwg & 7;
  const int xcd = orig & 7, idx = orig >> 3;
  const int wg = (xcd < r8 ? xcd * (q8 + 1) : r8 * (q8 + 1) + (xcd - r8) * q8) + idx;
  const int tm = wg / ntn, tn = wg % ntn;
  const size_t rowB = (size_t)tm * 256;
  const size_t colB = (size_t)tn * 256;

  // staging geometry: wave stages rows wid*8 + l/8 of a unit; source k-granule
  // pre-swizzled so linear LDS dest realizes (row, kg^(row&7)) storage.
  const int srow = wid * 8 + (l >> 3);
  const int skofs = ((l & 7) ^ (l >> 3)) * 8;   // elements

  // read geometry: lane reads row (l&15), wants kg = (l>>4)+kk*4, applies XOR
  const int arow = l & 15;
  const int aoff0 = arow * 128 + (((l >> 4) + 0) ^ (arow & 7)) * 16;
  const int aoff1 = arow * 128 + (((l >> 4) + 4) ^ (arow & 7)) * 16;

  floatx4 acc[8][4];
  #pragma unroll
  for (int m = 0; m < 8; ++m)
    #pragma unroll
    for (int n = 0; n < 4; ++n)
      acc[m][n] = (floatx4){0.f, 0.f, 0.f, 0.f};

  short8 aF[4][2], bF0[2][2], bF1[2][2];

  // prologue: stage t0 -> buf0 (8 issues), t1 -> buf1 (8 issues)
  #pragma unroll
  for (int u = 0; u < 4; ++u) STAGE_AU(0, u, 0);
  #pragma unroll
  for (int u = 0; u < 4; ++u) STAGE_BU(0, u, 0);
  #pragma unroll
  for (int u = 0; u < 4; ++u) STAGE_AU(1, u, 64);
  #pragma unroll
  for (int u = 0; u < 4; ++u) STAGE_BU(1, u, 64);
  WAITV8; BAR;   // t0 landed (t1 may fly); all waves synced

  const int NI2 = K >> 7;   // pairs of K-tiles
  for (int i = 0; i < NI2; ++i) {
    const int k2 = i * 128 + 128;  // next pair's first tile
    const int k3 = i * 128 + 192;  // next pair's second tile
    const bool nxt = (i < NI2 - 1);

    // ph1
    LOAD_A(0, 0); LOAD_B(0, 0, bF0);
    BAR; MMQ(0, 0, bF0); BAR;
    // ph2
    LOAD_B(0, 1, bF1);
    BAR; MMQ(0, 1, bF1); BAR;
    // ph3
    LOAD_A(0, 1);
    BAR; MMQ(1, 1, bF1); BAR;
    // ph4: stage A(t2)->buf0; wait so buf1(t1) is landed before ph5 reads
    if (nxt) {
      #pragma unroll
      for (int u = 0; u < 4; ++u) STAGE_AU(0, u, k2);
    }
    BAR; MMQ(1, 0, bF0);
    if (nxt) { WAITV4; } else { WAITV0; }
    BAR;
    // ph5
    LOAD_A(1, 0); LOAD_B(1, 0, bF0);
    if (nxt) {
      #pragma unroll
      for (int u = 0; u < 4; ++u) STAGE_BU(0, u, k2);
    }
    BAR; MMQ(0, 0, bF0); BAR;
    // ph6
    LOAD_B(1, 1, bF1);
    BAR; MMQ(0, 1, bF1); BAR;
    // ph7
    LOAD_A(1, 1);
    BAR; MMQ(1, 1, bF1); BAR;
    // ph8: stage t3->buf1; wait so buf0(t2) is landed before next ph1
    if (nxt) {
      #pragma unroll
      for (int u = 0; u < 4; ++u) STAGE_AU(1, u, k3);
      #pragma unroll
      for (int u = 0; u < 4; ++u) STAGE_BU(1, u, k3);
    }
    BAR; MMQ(1, 0, bF0);
    if (nxt) { WAITV8; }
    BAR;
  }
  FENCE;

  // epilogue: acc[mi][ni] -> rows rowB+wm*128+mi*16+(l>>4)*4+j,
  //           cols colB+wn*64+ni*16+(l&15)
  #pragma unroll
  for (int mi = 0; mi < 8; ++mi) {
    #pragma unroll
    for (int ni = 0; ni < 4; ++ni) {
      const int rr = (int)rowB + wm * 128 + mi * 16 + (l >> 4) * 4;
      const int cc = (int)colB + wn * 64 + ni * 16 + (l & 15);
      const float bs = bias[cc];
      #pragma unroll
      for (int j = 0; j < 4; ++j) {
        float v = acc[mi][ni][j] + bs;
        if (EPI == 1) v = 0.5f * v * (1.0f + erff(v * 0.70710678118654752f));
        if (EPI == 2) {
          v += resid[(size_t)(rr + j) * Nn + cc];
          outf[(size_t)(rr + j) * Nn + cc] = v;
        } else {
          outb[(size_t)(rr + j) * Nn + cc] = f2bf(v);
        }
      }
    }
  }
}

// -------------------------- window attention (9x9) -------------------------
__global__ __launch_bounds__(256)
void attn9(const unsigned short* __restrict__ qkv,
           const float* __restrict__ bias_table,
           unsigned short* __restrict__ out) {
  __shared__ float qL[4][9][64];
  __shared__ float kL[4][9][64];
  __shared__ float vL[4][9][64];
  __shared__ float sL[4][9][10];

  const int lane = threadIdx.x & 63;
  const int wid = threadIdx.x >> 6;
  const int bh = blockIdx.x * 4 + wid;
  const int b = bh >> 3;
  const int h = bh & 7;

  const size_t base = (size_t)b * 9 * 1536 + h * 64 + lane;
  #pragma unroll
  for (int i = 0; i < 9; ++i) {
    qL[wid][i][lane] = bf2f(qkv[base + i * 1536]) * 0.125f;
    kL[wid][i][lane] = bf2f(qkv[base + i * 1536 + 512]);
    vL[wid][i][lane] = bf2f(qkv[base + i * 1536 + 1024]);
  }
  __syncthreads();

  #pragma unroll
  for (int p = 0; p < 2; ++p) {
    int pair = lane + p * 64;
    if (pair < 81) {
      int i = pair / 9, j = pair % 9;
      const floatx4* qi = (const floatx4*)qL[wid][i];
      const floatx4* kj = (const floatx4*)kL[wid][j];
      float dot = 0.f;
      #pragma unroll
      for (int d = 0; d < 16; ++d) {
        floatx4 a = qi[d], c = kj[d];
        dot += a[0]*c[0] + a[1]*c[1] + a[2]*c[2] + a[3]*c[3];
      }
      int dy = i / 3 - j / 3 + 2;
      int dx = i % 3 - j % 3 + 2;
      dot += bias_table[(dy * 5 + dx) * 8 + h];
      sL[wid][i][j] = dot;
    }
  }
  __syncthreads();

  if (lane < 9) {
    float m = -1e30f;
    #pragma unroll
    for (int j = 0; j < 9; ++j) m = fmaxf(m, sL[wid][lane][j]);
    float e[9], sum = 0.f;
    #pragma unroll
    for (int j = 0; j < 9; ++j) { e[j] = __expf(sL[wid][lane][j] - m); sum += e[j]; }
    float inv = 1.f / sum;
    #pragma unroll
    for (int j = 0; j < 9; ++j) sL[wid][lane][j] = e[j] * inv;
  }
  __syncthreads();

  const size_t obase = (size_t)b * 9 * 512 + h * 64 + lane;
  #pragma unroll
  for (int i = 0; i < 9; ++i) {
    float a = 0.f;
    #pragma unroll
    for (int j = 0; j < 9; ++j) a += sL[wid][i][j] * vL[wid][j][lane];
    out[obase + i * 512] = f2bf(a);
  }
}

// -------------------- depthwise 3x3 merge conv (9 -> 1) --------------------
__global__ __launch_bounds__(256)
void dwconv9(const float* __restrict__ x2, const float* __restrict__ wc,
             const float* __restrict__ bc, float* __restrict__ out) {
  int idx = blockIdx.x * 256 + threadIdx.x;  // local: b*512 + c
  int c = idx & 511;
  int b = idx >> 9;
  const float* xp = x2 + (size_t)b * 9 * 512 + c;
  float acc = bc[c];
  #pragma unroll
  for (int t = 0; t < 9; ++t) acc += xp[t * 512] * wc[c * 9 + t];
  out[idx] = acc;
}

// ---------------------------------------------------------------------------
extern "C" void kernel_launch(void* const* d_in, const int* in_sizes, int n_in,
                              void* d_out, int out_size, void* d_ws, size_t ws_size,
                              hipStream_t stream) {
  const float* x      = (const float*)d_in[0];
  const float* gamma1 = (const float*)d_in[1];
  const float* beta1  = (const float*)d_in[2];
  const float* w_qkv  = (const float*)d_in[3];
  const float* b_qkv  = (const float*)d_in[4];
  const float* bias_t = (const float*)d_in[5];
  const float* w_proj = (const float*)d_in[6];
  const float* b_proj = (const float*)d_in[7];
  const float* gamma2 = (const float*)d_in[8];
  const float* beta2  = (const float*)d_in[9];
  const float* w_fc1  = (const float*)d_in[10];
  const float* b_fc1  = (const float*)d_in[11];
  const float* w_fc2  = (const float*)d_in[12];
  const float* b_fc2  = (const float*)d_in[13];
  const float* w_conv = (const float*)d_in[14];
  const float* b_conv = (const float*)d_in[15];
  float* out = (float*)d_out;

  // ---- adaptive chunking: need = 6.29MB + M_C*10240 bytes ----
  static const int cand[6] = {73728, 36864, 18432, 9216, 4608, 2304};
  int M_C = 2304;
  for (int i = 0; i < 6; ++i) {
    size_t need = 6291456ull + (size_t)cand[i] * 10240ull;
    if (need <= ws_size) { M_C = cand[i]; break; }
  }
  const int nChunks = R_TOT / M_C;
  const int winC = M_C / 9;

  char* ws = (char*)d_ws;
  unsigned short* wqkvb  = (unsigned short*)(ws);
  unsigned short* wprojb = (unsigned short*)(ws + 1572864);
  unsigned short* wfc1b  = (unsigned short*)(ws + 2097152);
  unsigned short* wfc2b  = (unsigned short*)(ws + 4194304);
  char* base = ws + 6291456;
  const size_t szHB  = (size_t)M_C * 1024;   // M_C*512 bf16
  const size_t szQKV = (size_t)M_C * 3072;   // M_C*1536 bf16
  const size_t szX1  = (size_t)M_C * 2048;   // M_C*512 f32
  unsigned short* hb   = (unsigned short*)base;                 // also aob
  unsigned short* aob  = hb;
  unsigned short* qkvb = (unsigned short*)(base + szHB);
  unsigned short* h2b  = qkvb;                                  // reuse
  float* x2            = (float*)(base + szHB + szHB);          // inside qkvb region
  float* x1            = (float*)(base + szHB + szQKV);
  unsigned short* gb   = (unsigned short*)(base + szHB + szQKV + szX1);

  // 1. weights -> bf16 (once)
  cvt4<<<768, 256, 0, stream>>>(w_qkv, wqkvb);
  cvt4<<<256, 256, 0, stream>>>(w_proj, wprojb);
  cvt4<<<1024, 256, 0, stream>>>(w_fc1, wfc1b);
  cvt4<<<1024, 256, 0, stream>>>(w_fc2, wfc2b);

  const int mt256 = M_C / 256;
  for (int ch = 0; ch < nChunks; ++ch) {
    const size_t rOff = (size_t)ch * M_C;
    const float* xC = x + rOff * 512;
    float* outC = out + (size_t)ch * winC * 512;

    ln_bf16<<<M_C / 4, 256, 0, stream>>>(xC, gamma1, beta1, hb);
    gemm8p<0><<<dim3(mt256 * 6), 512, 0, stream>>>(hb, wqkvb, b_qkv, nullptr, qkvb, nullptr, 512, 1536, 6);
    attn9<<<winC * 2, 256, 0, stream>>>(qkvb, bias_t, aob);
    gemm8p<2><<<dim3(mt256 * 2), 512, 0, stream>>>(aob, wprojb, b_proj, xC, nullptr, x1, 512, 512, 2);
    ln_bf16<<<M_C / 4, 256, 0, stream>>>(x1, gamma2, beta2, h2b);
    gemm8p<1><<<dim3(mt256 * 8), 512, 0, stream>>>(h2b, wfc1b, b_fc1, nullptr, gb, nullptr, 512, 2048, 8);
    gemm8p<2><<<dim3(mt256 * 2), 512, 0, stream>>>(gb, wfc2b, b_fc2, x1, nullptr, x2, 2048, 512, 2);
    dwconv9<<<winC * 2, 256, 0, stream>>>(x2, w_conv, b_conv, outC);
  }
}